// Round 2
// baseline (2370.297 us; speedup 1.0000x reference)
//
#include <hip/hip_runtime.h>
#include <stdint.h>
#include <stddef.h>

// ---------------------------------------------------------------------------
// MPSLayer: out[b] = x0·w0 -> 126x ( v' = einsum('bd,dfe,be->bf', v, W_i, x_i) )
//                 -> einsum('bd,df,bf->b', v, w_last, x_last)
//
// Strategy: per-site GEMM  v'[b,f] = sum_k P[b,k] * Wp[k,f],  k=(d,e), K=4096,
// with P[b,k] = v[b,d]*x[b,e] formed in registers (v_pk_mul_f16).
// fp16 everywhere on the MFMA path (bf16 would fail the 2%-of-absmax check;
// fp16 chain error ~0.6%), fp32 accumulate + fp32 v carry.
//
// Main kernel: 32 WGs x 4 waves, 16 batches/wave, full-K per wave.
// W streamed as 64KB chunks (double-buffered LDS) via global_load_lds with
// the bank-conflict swizzle PRE-APPLIED in global layout by prep_w
// (linear dest + pre-swizzled source + swizzled ds_read = rule 21).
// ---------------------------------------------------------------------------

typedef _Float16 half8   __attribute__((ext_vector_type(8)));
typedef _Float16 half2_t __attribute__((ext_vector_type(2)));
typedef float    floatx4 __attribute__((ext_vector_type(4)));

#define NMID      126
#define CHUNK_HW  32768           // halfwords per 64KB chunk: [64 f][512 kk]
#define NCHUNK    (NMID * 8)      // 8 K-chunks of 512 per site (K=4096)

// ws layout (bytes)
#define WP_BYTES  66060288u       // 126*4096*64 f16
#define XT_BYTES  33554432u       // 128*2048*64 f16

__device__ inline half2_t mk2(float f) {
  _Float16 h = (_Float16)f;
  half2_t r; r[0] = h; r[1] = h; return r;
}
__device__ inline half2_t h2of(half8 v, int j) {
  half2_t r; r[0] = v[2*j]; r[1] = v[2*j+1]; return r;
}
__device__ inline void stage16(const _Float16* gsrc, _Float16* lds_dst) {
  // per-lane global src; wave-uniform LDS dest (HW stores lane L at dst+L*16B)
  __builtin_amdgcn_global_load_lds(
      (const __attribute__((address_space(1))) uint32_t*)gsrc,
      (__attribute__((address_space(3))) uint32_t*)lds_dst,
      16, 0, 0);
}

// --- prep 1: w_mid fp32 [i][d][f][e] -> Wp f16 [i][c][f][kk^swz], k=d*64+e --
__global__ void prep_w(const float* __restrict__ wm, _Float16* __restrict__ Wp) {
  const size_t t    = (size_t)blockIdx.x * 256 + threadIdx.x;   // 4,128,768 thr
  const size_t base = t * 8;
  const int i   = (int)(base >> 18);
  const int r   = (int)(base & 262143);
  const int c   = r >> 15;
  const int r2  = r & 32767;
  const int f   = r2 >> 9;
  const int kk0 = r2 & 511;                 // multiple of 8
  const int k   = c * 512 + kk0;
  const int d   = k >> 6;
  const int e0  = k & 63;                   // multiple of 8
  const float* src = wm + ((((size_t)i * 64 + d) * 64 + f) * 64 + e0);
  floatx4 s0 = *(const floatx4*)src;
  floatx4 s1 = *(const floatx4*)(src + 4);
  half8 o;
  o[0]=(_Float16)s0[0]; o[1]=(_Float16)s0[1]; o[2]=(_Float16)s0[2]; o[3]=(_Float16)s0[3];
  o[4]=(_Float16)s1[0]; o[5]=(_Float16)s1[1]; o[6]=(_Float16)s1[2]; o[7]=(_Float16)s1[3];
  // swizzle: halfword index ^= (f&7)<<3  (== byte ^ ((f&7)<<4))
  const size_t hw = (size_t)i * 262144 + (size_t)c * 32768
                  + (size_t)f * 512 + (size_t)(kk0 ^ ((f & 7) << 3));
  *(half8*)(Wp + hw) = o;
}

// --- prep 2: x fp32 [b][i][e] -> xT f16 [i][b][e] ---------------------------
__global__ void prep_x(const float* __restrict__ x, _Float16* __restrict__ xT) {
  const size_t t    = (size_t)blockIdx.x * 256 + threadIdx.x;   // 2,097,152 thr
  const size_t base = t * 8;
  const int i  = (int)(base >> 17);
  const int r  = (int)(base & 131071);
  const int b  = r >> 6;
  const int e0 = r & 63;
  const float* src = x + ((size_t)b * 8192 + (size_t)i * 64 + e0);
  floatx4 s0 = *(const floatx4*)src;
  floatx4 s1 = *(const floatx4*)(src + 4);
  half8 o;
  o[0]=(_Float16)s0[0]; o[1]=(_Float16)s0[1]; o[2]=(_Float16)s0[2]; o[3]=(_Float16)s0[3];
  o[4]=(_Float16)s1[0]; o[5]=(_Float16)s1[1]; o[6]=(_Float16)s1[2]; o[7]=(_Float16)s1[3];
  *(half8*)(xT + base) = o;
}

// --- prep 3: v0[b][d] = sum_f x[b][0][f] * w0[f][d]   (exact fp32) ----------
__global__ void prep_v0(const float* __restrict__ x, const float* __restrict__ w0,
                        float* __restrict__ v0) {
  const int b = blockIdx.x * 4 + (threadIdx.x >> 6);
  const int d = threadIdx.x & 63;
  const float* xr = x + (size_t)b * 8192;
  float s = 0.f;
  #pragma unroll
  for (int f = 0; f < 64; ++f) s += xr[f] * w0[f * 64 + d];
  v0[b * 64 + d] = s;
}

// --- main: persistent chain, 32 WGs x 256 thr (4 waves x 16 b) --------------
__global__ __launch_bounds__(256, 1) void mps_main(
    const _Float16* __restrict__ Wp, const _Float16* __restrict__ xT,
    const float* __restrict__ v0, const float* __restrict__ wlast,
    const float* __restrict__ x, float* __restrict__ out)
{
  __shared__ _Float16 wbuf[2 * CHUNK_HW];   // 128 KiB: W chunk double buffer
  __shared__ float    vbuf[4 * 16 * 68];    // 17 KiB: per-wave v (pad 68)

  const int tid  = threadIdx.x;
  const int w    = tid >> 6, lane = tid & 63;
  const int bl   = lane & 15, kg = lane >> 4;       // MFMA row / k-group
  const int bgrp = (int)blockIdx.x * 64 + w * 16;   // wave's 16 batches
  float* vb = vbuf + w * (16 * 68);

  // v <- v0 (fp32)
  for (int t = lane; t < 1024; t += 64) {
    int rr = t >> 6, d = t & 63;
    vb[rr * 68 + d] = v0[(bgrp + rr) * 64 + d];
  }

  // x fragment pointers: xT[site][b][e], lane covers e = kg*8..+7 (+32)
  const _Float16* xrow = xT + (size_t)(bgrp + bl) * 64 + kg * 8;
  half8 xvA = *(const half8*)(xrow + 131072);        // site 0 uses x-site 1
  half8 xvB = *(const half8*)(xrow + 131072 + 32);

  // stage chunk 0
  {
    const _Float16* src = Wp + (size_t)w * 8192 + lane * 8;
    _Float16* dst = wbuf + w * 8192;
    #pragma unroll
    for (int it = 0; it < 16; ++it) stage16(src + it * 512, dst + it * 512);
  }
  __syncthreads();

  floatx4 acc[4] = {};
  #pragma unroll 1
  for (int cc = 0; cc < NCHUNK; ++cc) {
    const int c8 = cc & 7;
    if (cc + 1 < NCHUNK) {                 // stage next chunk (other buffer)
      const _Float16* src = Wp + (size_t)(cc + 1) * CHUNK_HW + w * 8192 + lane * 8;
      _Float16* dst = wbuf + ((cc + 1) & 1) * CHUNK_HW + w * 8192;
      #pragma unroll
      for (int it = 0; it < 16; ++it) stage16(src + it * 512, dst + it * 512);
    }
    // v for this chunk's 8 d's (d = c8*8 .. +7), broadcast as half2
    floatx4 va0 = *(const floatx4*)(vb + bl * 68 + c8 * 8);
    floatx4 va1 = *(const floatx4*)(vb + bl * 68 + c8 * 8 + 4);
    half2_t vh[8];
    vh[0]=mk2(va0[0]); vh[1]=mk2(va0[1]); vh[2]=mk2(va0[2]); vh[3]=mk2(va0[3]);
    vh[4]=mk2(va1[0]); vh[5]=mk2(va1[1]); vh[6]=mk2(va1[2]); vh[7]=mk2(va1[3]);
    const char* wbp = (const char*)(wbuf + (cc & 1) * CHUNK_HW);
    #pragma unroll
    for (int ks = 0; ks < 16; ++ks) {
      const int dloc = ks >> 1;
      const half8 xc = (ks & 1) ? xvB : xvA;    // e-half per k-window
      half2_t a0 = vh[dloc] * h2of(xc, 0);      // v_pk_mul_f16: P = v*x
      half2_t a1 = vh[dloc] * h2of(xc, 1);
      half2_t a2 = vh[dloc] * h2of(xc, 2);
      half2_t a3 = vh[dloc] * h2of(xc, 3);
      half8 af;
      af[0]=a0[0]; af[1]=a0[1]; af[2]=a1[0]; af[3]=a1[1];
      af[4]=a2[0]; af[5]=a2[1]; af[6]=a3[0]; af[7]=a3[1];
      const int kkb = ks * 32 + kg * 8;
      #pragma unroll
      for (int nt = 0; nt < 4; ++nt) {
        const int f = nt * 16 + bl;
        const int byteoff = ((f * 512 + kkb) * 2) ^ ((f & 7) << 4);
        half8 bf = *(const half8*)(wbp + byteoff);
        acc[nt] = __builtin_amdgcn_mfma_f32_16x16x32_f16(af, bf, acc[nt], 0, 0, 0);
      }
    }
    __syncthreads();
    if (c8 == 7) {                               // site boundary
      const int site = cc >> 3;
      // C-frag: row(b) = kg*4+reg, col(f) = nt*16+bl  -> transpose via LDS
      #pragma unroll
      for (int nt = 0; nt < 4; ++nt) {
        #pragma unroll
        for (int r = 0; r < 4; ++r)
          vb[(kg * 4 + r) * 68 + nt * 16 + bl] = acc[nt][r];
        acc[nt] = (floatx4){0.f, 0.f, 0.f, 0.f};
      }
      const size_t xo = (size_t)(site + 2) * 131072;  // next site's x (<=127)
      xvA = *(const half8*)(xrow + xo);
      xvB = *(const half8*)(xrow + xo + 32);
    }
  }

  // epilogue: out[b] = sum_{d,f} v[b,d] * wlast[d,f] * x[b,127,f]  (pure fp32,
  // reads the ORIGINAL fp32 x for the last site — one less rounding source)
  const float* xe = x + (size_t)(bgrp + bl) * 8192 + 127 * 64;
  float xr[64];
  #pragma unroll
  for (int q = 0; q < 16; ++q) {
    floatx4 t4 = *(const floatx4*)(xe + q * 4);
    xr[q*4+0] = t4[0]; xr[q*4+1] = t4[1]; xr[q*4+2] = t4[2]; xr[q*4+3] = t4[3];
  }
  float part = 0.f;
  #pragma unroll
  for (int dd = 0; dd < 16; ++dd) {
    const int d = kg * 16 + dd;                  // lane groups split d
    const float vd = vb[bl * 68 + d];
    float s = 0.f;
    #pragma unroll
    for (int ff = 0; ff < 64; ++ff) s += wlast[d * 64 + ff] * xr[ff];
    part += vd * s;
  }
  part += __shfl_xor(part, 16, 64);
  part += __shfl_xor(part, 32, 64);
  if (kg == 0) out[bgrp + bl] = part;
}

// ---------------------------------------------------------------------------
extern "C" void kernel_launch(void* const* d_in, const int* in_sizes, int n_in,
                              void* d_out, int out_size, void* d_ws, size_t ws_size,
                              hipStream_t stream) {
  const float* x     = (const float*)d_in[0];   // [2048][128][64]
  const float* w0    = (const float*)d_in[1];   // [64][64]
  const float* wmid  = (const float*)d_in[2];   // [126][64][64][64]
  const float* wlast = (const float*)d_in[3];   // [64][64]
  float* out = (float*)d_out;                   // [2048]

  _Float16* Wp = (_Float16*)d_ws;
  _Float16* xT = (_Float16*)((char*)d_ws + WP_BYTES);
  float*    v0 = (float*)((char*)d_ws + WP_BYTES + XT_BYTES);
  // total ws use: ~100.1 MB

  prep_w <<<16128, 256, 0, stream>>>(wmid, Wp);
  prep_x <<<8192,  256, 0, stream>>>(x, xT);
  prep_v0<<<512,   256, 0, stream>>>(x, w0, v0);
  mps_main<<<32,   256, 0, stream>>>(Wp, xT, v0, wlast, x, out);
}

// Round 3
// 1559.771 us; speedup vs baseline: 1.5196x; 1.5196x over previous
//
#include <hip/hip_runtime.h>
#include <stdint.h>
#include <stddef.h>

// ---------------------------------------------------------------------------
// MPSLayer, site-stepped formulation.
//
// Round-2 post-mortem: persistent 32-WG chain kernel is walled at ~66MB of W
// ingest PER CU (12.6 B/cyc effective). Fix: one launch per site (stream order
// provides the chain dependency), each a [2048 x 4096] @ [4096 x 64] GEMM
// k-split 4-way across WGs; per-WG W ingest drops to 128 KB/site from L2/LLC.
// Partials (4 x 2048 x 64 fp32) ping-pong in ws; next site sums on load.
// fp16 MFMA path (verified round 2: absmax 0.078 < 0.1825), fp32 carry.
// No LDS staging of W: direct coalesced B-frag loads (kills bank conflicts
// and the vmcnt(0)+barrier drain).
// ---------------------------------------------------------------------------

typedef _Float16 half8   __attribute__((ext_vector_type(8)));
typedef _Float16 half2_t __attribute__((ext_vector_type(2)));
typedef float    floatx4 __attribute__((ext_vector_type(4)));

#define WP_BYTES  66060288u          // 126*128*64*4*8 halfwords * 2B
#define P_ELEMS   524288             // 4 * 2048 * 64 floats (2 MB)
#define BSTRIDE   131072             // 2048*64, one k-quarter partial plane

__device__ inline half2_t h2of(half8 v, int j) {
  half2_t r; r[0] = v[2*j]; r[1] = v[2*j+1]; return r;
}
__device__ inline half8 cvt8(floatx4 a, floatx4 b) {
  half8 o;
  o[0]=(_Float16)a[0]; o[1]=(_Float16)a[1]; o[2]=(_Float16)a[2]; o[3]=(_Float16)a[3];
  o[4]=(_Float16)b[0]; o[5]=(_Float16)b[1]; o[6]=(_Float16)b[2]; o[7]=(_Float16)b[3];
  return o;
}

// --- prep: Wp[s][KT 128][f 64][kg 4][j 8] = W[d=KT>>1][f][e=(KT&1)*32+kg*8+j]
// Linear in thread id: hw addr = t*8. Coalesced read (8 consecutive e) & write.
__global__ void prep_wp(const float* __restrict__ wm, _Float16* __restrict__ Wp) {
  const int t  = blockIdx.x * 256 + threadIdx.x;   // 4,128,768 threads
  const int kg = t & 3;
  const int f  = (t >> 2) & 63;
  const int kt = (t >> 8) & 127;
  const int s  = t >> 15;
  const int d  = kt >> 1;
  const int e0 = (kt & 1) * 32 + kg * 8;
  const float* src = wm + ((((size_t)s * 64 + d) * 64 + f) * 64 + e0);
  floatx4 a = *(const floatx4*)src;
  floatx4 b = *(const floatx4*)(src + 4);
  *(half8*)(Wp + (size_t)t * 8) = cvt8(a, b);
}

// --- prep: v0[b][d] = sum_f x[b,0,f] * w0[f,d]  (exact fp32) ----------------
__global__ void prep_v0(const float* __restrict__ x, const float* __restrict__ w0,
                        float* __restrict__ v0) {
  const int b = blockIdx.x * 4 + (threadIdx.x >> 6);
  const int d = threadIdx.x & 63;
  const float* xr = x + (size_t)b * 8192;
  float s = 0.f;
  #pragma unroll
  for (int f = 0; f < 64; ++f) s += xr[f] * w0[f * 64 + d];
  v0[b * 64 + d] = s;
}

// --- one site: partial[kq][b][f] = sum_{d in kq-slice, e} u[b,d] W[d,f,e] x[b,e]
// grid 128 = 32 b-tiles x 4 k-quarters; 4 waves split the quarter's k further.
__global__ __launch_bounds__(256) void site_step(
    const _Float16* __restrict__ Wp, const float* __restrict__ x,
    const float* __restrict__ uprev, float* __restrict__ upart,
    int s, int nprev)
{
  __shared__ float ub[64 * 17];        // u slice [64 b][16 d], padded
  __shared__ float red[4 * 64 * 68];   // per-wave partial C for reduction

  const int tid = threadIdx.x;
  const int w = tid >> 6, lane = tid & 63;
  const int c15 = lane & 15, kg = lane >> 4;
  const int kq = (int)blockIdx.x & 3, bt = (int)blockIdx.x >> 2;
  const int b0 = bt * 64;
  const int xsite = s + 1;             // middle site i uses x[:, i+1]

  // load u slice (sum nprev k-quarter partials of previous site)
  for (int t = tid; t < 1024; t += 256) {
    const int bb = t >> 4, dl = t & 15;
    const int gi = (b0 + bb) * 64 + kq * 16 + dl;
    float v;
    if (nprev == 1) v = uprev[gi];
    else v = uprev[gi] + uprev[BSTRIDE + gi] + uprev[2*BSTRIDE + gi] + uprev[3*BSTRIDE + gi];
    ub[bb * 17 + dl] = v;
  }
  __syncthreads();

  // x fragments (fp32 -> fp16 on the fly): e-halves 0..31 / 32..63
  half8 xA[4], xB[4];
  #pragma unroll
  for (int mt = 0; mt < 4; ++mt) {
    const float* xp = x + ((size_t)(b0 + mt * 16 + c15) * 128 + xsite) * 64 + kg * 8;
    xA[mt] = cvt8(*(const floatx4*)xp,        *(const floatx4*)(xp + 4));
    xB[mt] = cvt8(*(const floatx4*)(xp + 32), *(const floatx4*)(xp + 36));
  }

  // main: 8 k-tiles of 32 per wave; d-local = w*4 + (kt>>1)
  floatx4 C[4][4] = {};
  const int ktbase = kq * 32 + w * 8;  // global 32-k tile index base
  const _Float16* wbase = Wp + ((size_t)s * 128 + ktbase) * 2048;
  #pragma unroll
  for (int kt = 0; kt < 8; ++kt) {
    const int dl = w * 4 + (kt >> 1);
    half8 bf[4];
    #pragma unroll
    for (int nt = 0; nt < 4; ++nt)
      bf[nt] = *(const half8*)(wbase + ((size_t)kt * 64 + nt * 16 + c15) * 32 + kg * 8);
    #pragma unroll
    for (int mt = 0; mt < 4; ++mt) {
      const float us = ub[(mt * 16 + c15) * 17 + dl];
      const _Float16 uh = (_Float16)us;
      half2_t uu; uu[0] = uh; uu[1] = uh;
      const half8 xc = (kt & 1) ? xB[mt] : xA[mt];
      half2_t p0 = uu * h2of(xc, 0), p1 = uu * h2of(xc, 1);
      half2_t p2 = uu * h2of(xc, 2), p3 = uu * h2of(xc, 3);
      half8 af;
      af[0]=p0[0]; af[1]=p0[1]; af[2]=p1[0]; af[3]=p1[1];
      af[4]=p2[0]; af[5]=p2[1]; af[6]=p3[0]; af[7]=p3[1];
      #pragma unroll
      for (int nt = 0; nt < 4; ++nt)
        C[mt][nt] = __builtin_amdgcn_mfma_f32_16x16x32_f16(af, bf[nt], C[mt][nt], 0, 0, 0);
    }
  }

  // cross-wave reduce (4 waves split this quarter's k) then store partial
  #pragma unroll
  for (int mt = 0; mt < 4; ++mt)
    #pragma unroll
    for (int nt = 0; nt < 4; ++nt)
      #pragma unroll
      for (int r = 0; r < 4; ++r)
        red[(w * 64 + mt * 16 + kg * 4 + r) * 68 + nt * 16 + c15] = C[mt][nt][r];
  __syncthreads();

  {
    const int bb = tid >> 2, f0 = (tid & 3) * 16;
    float* op = upart + (size_t)kq * BSTRIDE + (size_t)(b0 + bb) * 64 + f0;
    #pragma unroll
    for (int q = 0; q < 4; ++q) {
      floatx4 a0 = *(const floatx4*)&red[(0 * 64 + bb) * 68 + f0 + q * 4];
      floatx4 a1 = *(const floatx4*)&red[(1 * 64 + bb) * 68 + f0 + q * 4];
      floatx4 a2 = *(const floatx4*)&red[(2 * 64 + bb) * 68 + f0 + q * 4];
      floatx4 a3 = *(const floatx4*)&red[(3 * 64 + bb) * 68 + f0 + q * 4];
      *(floatx4*)(op + q * 4) = a0 + a1 + a2 + a3;
    }
  }
}

// --- finalize: out[b] = sum_d (sum_kq part[kq][b][d]) * (sum_f wlast[d,f] x[b,127,f])
__global__ void finalize(const float* __restrict__ part, const float* __restrict__ x,
                         const float* __restrict__ wlast, float* __restrict__ out) {
  const int w = threadIdx.x >> 6, lane = threadIdx.x & 63;
  const int b = (int)blockIdx.x * 4 + w;
  const size_t gi = (size_t)b * 64 + lane;
  const float u = part[gi] + part[BSTRIDE + gi] + part[2*BSTRIDE + gi] + part[3*BSTRIDE + gi];
  const float* xr = x + (size_t)b * 8192 + 127 * 64;
  const float* wr = wlast + lane * 64;
  float z = 0.f;
  #pragma unroll
  for (int f = 0; f < 64; f += 4) {
    floatx4 wv = *(const floatx4*)(wr + f);
    floatx4 xv = *(const floatx4*)(xr + f);
    z += wv[0]*xv[0] + wv[1]*xv[1] + wv[2]*xv[2] + wv[3]*xv[3];
  }
  float p = u * z;
  #pragma unroll
  for (int m = 32; m; m >>= 1) p += __shfl_xor(p, m, 64);
  if (lane == 0) out[b] = p;
}

// ---------------------------------------------------------------------------
extern "C" void kernel_launch(void* const* d_in, const int* in_sizes, int n_in,
                              void* d_out, int out_size, void* d_ws, size_t ws_size,
                              hipStream_t stream) {
  const float* x     = (const float*)d_in[0];   // [2048][128][64]
  const float* w0    = (const float*)d_in[1];   // [64][64]
  const float* wmid  = (const float*)d_in[2];   // [126][64][64][64]
  const float* wlast = (const float*)d_in[3];   // [64][64]
  float* out = (float*)d_out;                   // [2048]

  _Float16* Wp  = (_Float16*)d_ws;
  float* part0  = (float*)((char*)d_ws + WP_BYTES);
  float* part1  = part0 + P_ELEMS;
  float* v0     = part1 + P_ELEMS;
  // ws use: 66.06 MB + 2*2 MB + 0.5 MB = 70.8 MB (< 95.5 MB proven in round 2)

  prep_wp<<<16128, 256, 0, stream>>>(wmid, Wp);
  prep_v0<<<512,   256, 0, stream>>>(x, w0, v0);

  for (int s = 0; s < 126; ++s) {
    const float* up = (s == 0) ? v0 : ((s & 1) ? part0 : part1);
    float* po = (s & 1) ? part1 : part0;
    site_step<<<128, 256, 0, stream>>>(Wp, x, up, po, s, (s == 0) ? 1 : 4);
  }
  // s=125 (odd) wrote part1
  finalize<<<512, 256, 0, stream>>>(part1, x, wlast, out);
}